// Round 3
// baseline (210.470 us; speedup 1.0000x reference)
//
#include <hip/hip_runtime.h>
#include <math.h>

#define BB 32
#define CC 2048
#define NN 784          // 28*28
#define NF4 196         // float4 per (b,c) row
#define MM 4
#define TILE 8
#define LAMBDA_ 1e-3f
#define EPS_ 1e-10f
#define LOG1E4 9.210340371976184f
#define NORM_BLOCKS (BB * CC / 4)   // 16384

__device__ __forceinline__ float wred(float v) {
#pragma unroll
  for (int off = 32; off > 0; off >>= 1) v += __shfl_down(v, off, 64);
  return v;
}

// ---- K1: fused norm + partial-s over c-chunks + peW side blocks ----
// Single read of x: register-tile 8 channels, sq-reduce -> inv_norm, then dot
// from the SAME registers. Deterministic (fixed reduction trees, no atomics).
template <int NCH>
__global__ __launch_bounds__(256) void k_sacc_fused(const float* __restrict__ x,
                                                    const float* __restrict__ W,
                                                    float* __restrict__ inv_norm,
                                                    float* __restrict__ peW,
                                                    float4* __restrict__ sPart4) {
  int ch = blockIdx.x;
  int b  = blockIdx.y;
  int t  = threadIdx.x;
  int lane = t & 63;
  int wv   = t >> 6;

  if (ch == NCH) {
    // peW[m,n] = sum_c pe[n,c]*W[m,c]; this block covers a 25-wide n slice.
    const int NPS = (NN + BB - 1) / BB;   // 25
    int n0 = b * NPS, n1 = (n0 + NPS < NN) ? n0 + NPS : NN;
    int m = wv;
    for (int n = n0; n < n1; ++n) {
      float acc = 0.f;
      for (int c = lane; c < CC; c += 64) {
        float di  = __expf(-((float)(c & ~1) * (1.f / CC)) * LOG1E4);
        float arg = (float)n * di;
        float pe  = (c & 1) ? __cosf(arg) : __sinf(arg);
        acc += pe * W[m * CC + c];
      }
      acc = wred(acc);
      if (lane == 0) peW[m * NN + n] = acc;
    }
    return;
  }

  const int cper = CC / NCH;
  bool valid = t < NF4;
  int tt = valid ? t : 0;
  const float4* xb = (const float4*)(x + (size_t)b * CC * NN);

  __shared__ float red[4][TILE];
  __shared__ float inv_s[TILE];

  float4 a0{0,0,0,0}, a1{0,0,0,0}, a2{0,0,0,0}, a3{0,0,0,0};
  int c0 = ch * cper;

  for (int tile = 0; tile < cper / TILE; ++tile) {
    int cb = c0 + tile * TILE;
    float4 xv[TILE];
    float sq[TILE];
#pragma unroll
    for (int i = 0; i < TILE; ++i) {
      float4 v = xb[(size_t)(cb + i) * NF4 + tt];
      if (!valid) { v.x = 0.f; v.y = 0.f; v.z = 0.f; v.w = 0.f; }
      xv[i] = v;
      sq[i] = v.x * v.x + v.y * v.y + v.z * v.z + v.w * v.w;
    }
#pragma unroll
    for (int i = 0; i < TILE; ++i) sq[i] = wred(sq[i]);
    if (lane == 0) {
#pragma unroll
      for (int i = 0; i < TILE; ++i) red[wv][i] = sq[i];
    }
    __syncthreads();
    if (t < TILE) {
      float s = red[0][t] + red[1][t] + red[2][t] + red[3][t];
      float inv = 1.f / fmaxf(sqrtf(s), EPS_);
      inv_s[t] = inv;
      inv_norm[b * CC + cb + t] = inv;
    }
    __syncthreads();
    // dot from registers; next tile's LDS writes are ordered by its barrier 1.
#pragma unroll
    for (int i = 0; i < TILE; ++i) {
      int c = cb + i;
      float iw = inv_s[i];
      float w0 = iw * W[0 * CC + c];
      float w1 = iw * W[1 * CC + c];
      float w2 = iw * W[2 * CC + c];
      float w3 = iw * W[3 * CC + c];
      a0.x += xv[i].x * w0; a0.y += xv[i].y * w0; a0.z += xv[i].z * w0; a0.w += xv[i].w * w0;
      a1.x += xv[i].x * w1; a1.y += xv[i].y * w1; a1.z += xv[i].z * w1; a1.w += xv[i].w * w1;
      a2.x += xv[i].x * w2; a2.y += xv[i].y * w2; a2.z += xv[i].z * w2; a2.w += xv[i].w * w2;
      a3.x += xv[i].x * w3; a3.y += xv[i].y * w3; a3.z += xv[i].z * w3; a3.w += xv[i].w * w3;
    }
  }
  if (valid) {
    size_t base = (((size_t)b * NCH + ch) * MM) * NF4 + t;
    sPart4[base + 0 * NF4] = a0;
    sPart4[base + 1 * NF4] = a1;
    sPart4[base + 2 * NF4] = a2;
    sPart4[base + 3 * NF4] = a3;
  }
}

// ---- K2: hid4[(b*N+n)*4+m] = sigmoid(peW + sum_ch sPart) ----
template <int NCH>
__global__ __launch_bounds__(256) void k_hid(const float* __restrict__ sPart,
                                             const float* __restrict__ peW,
                                             float* __restrict__ hid4) {
  int n = blockIdx.x * 256 + threadIdx.x;
  int b = blockIdx.y;
  if (n >= NN) return;
  float h[MM];
#pragma unroll
  for (int m = 0; m < MM; ++m) {
    float s = peW[m * NN + n];
#pragma unroll
    for (int ch = 0; ch < NCH; ++ch)
      s += sPart[(((size_t)b * NCH + ch) * MM + m) * NN + n];
    h[m] = 1.f / (1.f + __expf(-s));
  }
  float4 hv = make_float4(h[0], h[1], h[2], h[3]);
  *(float4*)(hid4 + ((size_t)b * NN + n) * 4) = hv;
}

// ---- K3: out[b,c] = sum_m (inv*aX[m] + aP[m]) / (aD[m]+lambda) ----
__global__ __launch_bounds__(256) void k_out(const float* __restrict__ x,
                                             const float* __restrict__ hid4,
                                             const float* __restrict__ inv_norm,
                                             float* __restrict__ out) {
  int idx  = blockIdx.x * 4 + (threadIdx.x >> 6);   // (b*C+c)
  int lane = threadIdx.x & 63;
  int b = idx >> 11;
  int c = idx & (CC - 1);
  const float4* row = (const float4*)(x + (size_t)idx * NN);
  const float4* hb  = (const float4*)(hid4 + (size_t)b * NN * 4);
  float di = __expf(-((float)(c & ~1) * (1.0f / CC)) * LOG1E4);
  bool use_sin = !(c & 1);
  float aX0=0,aX1=0,aX2=0,aX3=0, aP0=0,aP1=0,aP2=0,aP3=0, aD0=0,aD1=0,aD2=0,aD3=0;
  for (int f = lane; f < NF4; f += 64) {
    float4 xv = row[f];
    int n = f * 4;
    float4 h0 = hb[n + 0], h1 = hb[n + 1], h2 = hb[n + 2], h3 = hb[n + 3];
    float a0 = (float)(n + 0) * di, a1 = (float)(n + 1) * di;
    float a2 = (float)(n + 2) * di, a3 = (float)(n + 3) * di;
    float p0 = use_sin ? __sinf(a0) : __cosf(a0);
    float p1 = use_sin ? __sinf(a1) : __cosf(a1);
    float p2 = use_sin ? __sinf(a2) : __cosf(a2);
    float p3 = use_sin ? __sinf(a3) : __cosf(a3);
    aX0 += xv.x*h0.x + xv.y*h1.x + xv.z*h2.x + xv.w*h3.x;
    aX1 += xv.x*h0.y + xv.y*h1.y + xv.z*h2.y + xv.w*h3.y;
    aX2 += xv.x*h0.z + xv.y*h1.z + xv.z*h2.z + xv.w*h3.z;
    aX3 += xv.x*h0.w + xv.y*h1.w + xv.z*h2.w + xv.w*h3.w;
    aP0 += p0*h0.x + p1*h1.x + p2*h2.x + p3*h3.x;
    aP1 += p0*h0.y + p1*h1.y + p2*h2.y + p3*h3.y;
    aP2 += p0*h0.z + p1*h1.z + p2*h2.z + p3*h3.z;
    aP3 += p0*h0.w + p1*h1.w + p2*h2.w + p3*h3.w;
    aD0 += h0.x*h0.x + h1.x*h1.x + h2.x*h2.x + h3.x*h3.x;
    aD1 += h0.y*h0.y + h1.y*h1.y + h2.y*h2.y + h3.y*h3.y;
    aD2 += h0.z*h0.z + h1.z*h1.z + h2.z*h2.z + h3.z*h3.z;
    aD3 += h0.w*h0.w + h1.w*h1.w + h2.w*h2.w + h3.w*h3.w;
  }
  aX0 = wred(aX0); aX1 = wred(aX1); aX2 = wred(aX2); aX3 = wred(aX3);
  aP0 = wred(aP0); aP1 = wred(aP1); aP2 = wred(aP2); aP3 = wred(aP3);
  aD0 = wred(aD0); aD1 = wred(aD1); aD2 = wred(aD2); aD3 = wred(aD3);
  if (lane == 0) {
    float inv = inv_norm[idx];
    float r = (inv * aX0 + aP0) / (aD0 + LAMBDA_)
            + (inv * aX1 + aP1) / (aD1 + LAMBDA_)
            + (inv * aX2 + aP2) / (aD2 + LAMBDA_)
            + (inv * aX3 + aP3) / (aD3 + LAMBDA_);
    if (isnan(r)) r = 0.f;
    else if (isinf(r)) r = (r > 0.f) ? 3.4028234663852886e38f : -3.4028234663852886e38f;
    out[idx] = r;
  }
}

extern "C" void kernel_launch(void* const* d_in, const int* in_sizes, int n_in,
                              void* d_out, int out_size, void* d_ws, size_t ws_size,
                              hipStream_t stream) {
  const float* x = (const float*)d_in[0];   // (B, C, S, S)
  const float* W = (const float*)d_in[1];   // (M, C, 1)
  float* out = (float*)d_out;               // (B, 1, C)
  float* ws  = (float*)d_ws;

  float* inv_norm = ws;                                   // B*C   = 65536
  float* peW      = inv_norm + (size_t)BB * CC;           // M*N   = 3136
  float* hid4     = peW + (size_t)MM * NN;                // B*N*M = 401408
  float* sPart    = hid4 + (size_t)BB * NN * MM;          // B*NCH*M*N

  const size_t base_floats = (size_t)BB * CC + MM * NN + (size_t)BB * NN * MM;
  const size_t need32 = (base_floats + (size_t)BB * 32 * MM * NN) * sizeof(float);
  const size_t need16 = (base_floats + (size_t)BB * 16 * MM * NN) * sizeof(float);

  if (ws_size >= need32) {
    k_sacc_fused<32><<<dim3(33, BB), 256, 0, stream>>>(x, W, inv_norm, peW, (float4*)sPart);
    k_hid<32><<<dim3(4, BB), 256, 0, stream>>>(sPart, peW, hid4);
  } else if (ws_size >= need16) {
    k_sacc_fused<16><<<dim3(17, BB), 256, 0, stream>>>(x, W, inv_norm, peW, (float4*)sPart);
    k_hid<16><<<dim3(4, BB), 256, 0, stream>>>(sPart, peW, hid4);
  } else {
    k_sacc_fused<8><<<dim3(9, BB), 256, 0, stream>>>(x, W, inv_norm, peW, (float4*)sPart);
    k_hid<8><<<dim3(4, BB), 256, 0, stream>>>(sPart, peW, hid4);
  }
  k_out<<<NORM_BLOCKS, 256, 0, stream>>>(x, hid4, inv_norm, out);
}

// Round 4
// 133.653 us; speedup vs baseline: 1.5748x; 1.5748x over previous
//
#include <hip/hip_runtime.h>
#include <math.h>

#define BB 32
#define CC 2048
#define NN 784          // 28*28
#define NF4 196         // float4 per (b,c) spatial row
#define MM 4
#define LAMBDA_ 1e-3f
#define EPS_ 1e-10f
#define LOG1E4 9.210340371976184f
#define NORM_BLOCKS (BB * CC / 4)   // 16384

__device__ __forceinline__ float wred(float v) {
#pragma unroll
  for (int off = 32; off > 0; off >>= 1) v += __shfl_down(v, off, 64);
  return v;
}

// ---- K1: peW[m,n] = sum_c pe[n,c] * W[m,c]  (batch-independent, tiny) ----
__global__ __launch_bounds__(256) void k_peW(const float* __restrict__ W,
                                             float* __restrict__ peW) {
  int n    = blockIdx.x;
  int m    = threadIdx.x >> 6;
  int lane = threadIdx.x & 63;
  float acc = 0.f;
  for (int c = lane; c < CC; c += 64) {
    float di  = __expf(-((float)(c & ~1) * (1.f / CC)) * LOG1E4);
    float arg = (float)n * di;
    float pe  = (c & 1) ? __cosf(arg) : __sinf(arg);
    acc += pe * W[m * CC + c];
  }
  acc = wred(acc);
  if (lane == 0) peW[m * NN + n] = acc;
}

// ---- K2: fused norm + partial dot, wave-private (NO LDS, NO barriers) ----
// One wave per channel-chunk: lanes cover the spatial row (4 float4 slots).
// Per channel: butterfly sumsq -> inv_norm, then FMA dot from same registers.
template <int NCH>
__global__ __launch_bounds__(256) void k_sacc2(const float* __restrict__ x,
                                               const float* __restrict__ W,
                                               float* __restrict__ inv_norm,
                                               float4* __restrict__ sPart4) {
  constexpr int CPER = CC / NCH;        // channels per wave (power of 2)
  int b    = blockIdx.y;
  int wv   = threadIdx.x >> 6;
  int lane = threadIdx.x & 63;
  int ch   = blockIdx.x * 4 + wv;
  int c0   = ch * CPER;
  const float4* xb = (const float4*)(x + ((size_t)b * CC + c0) * NN);
  const float4 z = make_float4(0.f, 0.f, 0.f, 0.f);

  float4 acc[MM][4];
#pragma unroll
  for (int m = 0; m < MM; ++m)
#pragma unroll
    for (int j = 0; j < 4; ++j) acc[m][j] = z;

  float4 xA[4], xB[4];

  auto LOAD = [&](float4* dst, int i) {
    const float4* p = xb + (size_t)i * NF4 + lane;
    dst[0] = p[0];
    dst[1] = p[64];
    dst[2] = p[128];
    dst[3] = (lane < (NF4 - 192)) ? p[192] : z;   // lanes 0..3 only
  };
  auto COMP = [&](const float4* v, int i) {
    int c = c0 + i;
    float sq = v[0].x * v[0].x + v[0].y * v[0].y + v[0].z * v[0].z + v[0].w * v[0].w
             + v[1].x * v[1].x + v[1].y * v[1].y + v[1].z * v[1].z + v[1].w * v[1].w
             + v[2].x * v[2].x + v[2].y * v[2].y + v[2].z * v[2].z + v[2].w * v[2].w
             + v[3].x * v[3].x + v[3].y * v[3].y + v[3].z * v[3].z + v[3].w * v[3].w;
#pragma unroll
    for (int o = 1; o < 64; o <<= 1) sq += __shfl_xor(sq, o, 64);
    float inv = 1.f / fmaxf(sqrtf(sq), EPS_);
    if (lane == 0) inv_norm[b * CC + c] = inv;
    float w0 = inv * W[0 * CC + c];
    float w1 = inv * W[1 * CC + c];
    float w2 = inv * W[2 * CC + c];
    float w3 = inv * W[3 * CC + c];
#pragma unroll
    for (int j = 0; j < 4; ++j) {
      float4 v4 = v[j];
      acc[0][j].x += v4.x * w0; acc[0][j].y += v4.y * w0; acc[0][j].z += v4.z * w0; acc[0][j].w += v4.w * w0;
      acc[1][j].x += v4.x * w1; acc[1][j].y += v4.y * w1; acc[1][j].z += v4.z * w1; acc[1][j].w += v4.w * w1;
      acc[2][j].x += v4.x * w2; acc[2][j].y += v4.y * w2; acc[2][j].z += v4.z * w2; acc[2][j].w += v4.w * w2;
      acc[3][j].x += v4.x * w3; acc[3][j].y += v4.y * w3; acc[3][j].z += v4.z * w3; acc[3][j].w += v4.w * w3;
    }
  };

  LOAD(xA, 0);
  for (int i = 0; i < CPER; i += 2) {
    LOAD(xB, i + 1);
    COMP(xA, i);
    LOAD(xA, (i + 2) & (CPER - 1));   // wraps to 0 on last iter (harmless reload)
    COMP(xB, i + 1);
  }

  size_t base = (((size_t)b * NCH + ch) * MM) * NF4;
#pragma unroll
  for (int m = 0; m < MM; ++m)
#pragma unroll
    for (int j = 0; j < 4; ++j) {
      int f = lane + 64 * j;
      if (f < NF4) sPart4[base + (size_t)m * NF4 + f] = acc[m][j];
    }
}

// ---- K3: hid4[(b*N+n)*4+m] = sigmoid(peW + sum_ch sPart) ----
template <int NCH>
__global__ __launch_bounds__(256) void k_hid(const float* __restrict__ sPart,
                                             const float* __restrict__ peW,
                                             float* __restrict__ hid4) {
  int n = blockIdx.x * 256 + threadIdx.x;
  int b = blockIdx.y;
  if (n >= NN) return;
  float h[MM];
#pragma unroll
  for (int m = 0; m < MM; ++m) {
    float s = peW[m * NN + n];
#pragma unroll 8
    for (int ch = 0; ch < NCH; ++ch)
      s += sPart[(((size_t)b * NCH + ch) * MM + m) * NN + n];
    h[m] = 1.f / (1.f + __expf(-s));
  }
  float4 hv = make_float4(h[0], h[1], h[2], h[3]);
  *(float4*)(hid4 + ((size_t)b * NN + n) * 4) = hv;
}

// ---- K4: out[b,c] = sum_m (inv*aX[m] + aP[m]) / (aD[m]+lambda) ----
__global__ __launch_bounds__(256) void k_out(const float* __restrict__ x,
                                             const float* __restrict__ hid4,
                                             const float* __restrict__ inv_norm,
                                             float* __restrict__ out) {
  int idx  = blockIdx.x * 4 + (threadIdx.x >> 6);   // (b*C+c)
  int lane = threadIdx.x & 63;
  int b = idx >> 11;
  int c = idx & (CC - 1);
  const float4* row = (const float4*)(x + (size_t)idx * NN);
  const float4* hb  = (const float4*)(hid4 + (size_t)b * NN * 4);
  float di = __expf(-((float)(c & ~1) * (1.0f / CC)) * LOG1E4);
  bool use_sin = !(c & 1);
  float aX0=0,aX1=0,aX2=0,aX3=0, aP0=0,aP1=0,aP2=0,aP3=0, aD0=0,aD1=0,aD2=0,aD3=0;
  for (int f = lane; f < NF4; f += 64) {
    float4 xv = row[f];
    int n = f * 4;
    float4 h0 = hb[n + 0], h1 = hb[n + 1], h2 = hb[n + 2], h3 = hb[n + 3];
    float a0 = (float)(n + 0) * di, a1 = (float)(n + 1) * di;
    float a2 = (float)(n + 2) * di, a3 = (float)(n + 3) * di;
    float p0 = use_sin ? __sinf(a0) : __cosf(a0);
    float p1 = use_sin ? __sinf(a1) : __cosf(a1);
    float p2 = use_sin ? __sinf(a2) : __cosf(a2);
    float p3 = use_sin ? __sinf(a3) : __cosf(a3);
    aX0 += xv.x*h0.x + xv.y*h1.x + xv.z*h2.x + xv.w*h3.x;
    aX1 += xv.x*h0.y + xv.y*h1.y + xv.z*h2.y + xv.w*h3.y;
    aX2 += xv.x*h0.z + xv.y*h1.z + xv.z*h2.z + xv.w*h3.z;
    aX3 += xv.x*h0.w + xv.y*h1.w + xv.z*h2.w + xv.w*h3.w;
    aP0 += p0*h0.x + p1*h1.x + p2*h2.x + p3*h3.x;
    aP1 += p0*h0.y + p1*h1.y + p2*h2.y + p3*h3.y;
    aP2 += p0*h0.z + p1*h1.z + p2*h2.z + p3*h3.z;
    aP3 += p0*h0.w + p1*h1.w + p2*h2.w + p3*h3.w;
    aD0 += h0.x*h0.x + h1.x*h1.x + h2.x*h2.x + h3.x*h3.x;
    aD1 += h0.y*h0.y + h1.y*h1.y + h2.y*h2.y + h3.y*h3.y;
    aD2 += h0.z*h0.z + h1.z*h1.z + h2.z*h2.z + h3.z*h3.z;
    aD3 += h0.w*h0.w + h1.w*h1.w + h2.w*h2.w + h3.w*h3.w;
  }
  aX0 = wred(aX0); aX1 = wred(aX1); aX2 = wred(aX2); aX3 = wred(aX3);
  aP0 = wred(aP0); aP1 = wred(aP1); aP2 = wred(aP2); aP3 = wred(aP3);
  aD0 = wred(aD0); aD1 = wred(aD1); aD2 = wred(aD2); aD3 = wred(aD3);
  if (lane == 0) {
    float inv = inv_norm[idx];
    float r = (inv * aX0 + aP0) / (aD0 + LAMBDA_)
            + (inv * aX1 + aP1) / (aD1 + LAMBDA_)
            + (inv * aX2 + aP2) / (aD2 + LAMBDA_)
            + (inv * aX3 + aP3) / (aD3 + LAMBDA_);
    if (isnan(r)) r = 0.f;
    else if (isinf(r)) r = (r > 0.f) ? 3.4028234663852886e38f : -3.4028234663852886e38f;
    out[idx] = r;
  }
}

extern "C" void kernel_launch(void* const* d_in, const int* in_sizes, int n_in,
                              void* d_out, int out_size, void* d_ws, size_t ws_size,
                              hipStream_t stream) {
  const float* x = (const float*)d_in[0];   // (B, C, S, S)
  const float* W = (const float*)d_in[1];   // (M, C, 1)
  float* out = (float*)d_out;               // (B, 1, C)
  float* ws  = (float*)d_ws;

  float* inv_norm = ws;                                   // B*C   = 65536
  float* peW      = inv_norm + (size_t)BB * CC;           // M*N   = 3136
  float* hid4     = peW + (size_t)MM * NN;                // B*N*M = 401408
  float* sPart    = hid4 + (size_t)BB * NN * MM;          // B*NCH*M*N

  const size_t base_floats = (size_t)BB * CC + MM * NN + (size_t)BB * NN * MM;
  const size_t need64 = (base_floats + (size_t)BB * 64 * MM * NN) * sizeof(float);
  const size_t need32 = (base_floats + (size_t)BB * 32 * MM * NN) * sizeof(float);

  k_peW<<<NN, 256, 0, stream>>>(W, peW);
  if (ws_size >= need64) {
    k_sacc2<64><<<dim3(16, BB), 256, 0, stream>>>(x, W, inv_norm, (float4*)sPart);
    k_hid<64><<<dim3(4, BB), 256, 0, stream>>>(sPart, peW, hid4);
  } else if (ws_size >= need32) {
    k_sacc2<32><<<dim3(8, BB), 256, 0, stream>>>(x, W, inv_norm, (float4*)sPart);
    k_hid<32><<<dim3(4, BB), 256, 0, stream>>>(sPart, peW, hid4);
  } else {
    k_sacc2<16><<<dim3(4, BB), 256, 0, stream>>>(x, W, inv_norm, (float4*)sPart);
    k_hid<16><<<dim3(4, BB), 256, 0, stream>>>(sPart, peW, hid4);
  }
  k_out<<<NORM_BLOCKS, 256, 0, stream>>>(x, hid4, inv_norm, out);
}